// Round 7
// baseline (268.487 us; speedup 1.0000x reference)
//
#include <hip/hip_runtime.h>

#define N_NODES 100000
#define N_EDGES 1600000
#define N_LABEL 200000
#define HID 128
#define OUT 5

typedef __attribute__((ext_vector_type(8))) short bf16x8;
typedef __attribute__((ext_vector_type(4))) float f32x4;

// ---- bf16 helpers (manual, RNE) -------------------------------------------
__device__ inline void bf2x(unsigned u, float& lo, float& hi) {
    lo = __uint_as_float(u << 16);
    hi = __uint_as_float(u & 0xffff0000u);
}
__device__ inline unsigned pack2(float a, float b) {
    unsigned ua = __float_as_uint(a), ub = __float_as_uint(b);
    ua = (ua + 0x7fffu + ((ua >> 16) & 1u)) >> 16;
    ub = (ub + 0x7fffu + ((ub >> 16) & 1u)) & 0xffff0000u;
    return ua | ub;
}
__device__ inline unsigned short bf1(float f) {
    unsigned u = __float_as_uint(f);
    return (unsigned short)((u + 0x7fffu + ((u >> 16) & 1u)) >> 16);
}

// ---------------------------------------------------------------------------
// K0: wt[n][k] = bf16(W[k][n])  (transpose + convert, one-time 64KB)
// ---------------------------------------------------------------------------
__global__ void k_prep(const float* __restrict__ Wg, unsigned short* __restrict__ wt) {
    int n = blockIdx.x;   // 128 blocks
    int k = threadIdx.x;  // 128 threads
    wt[n * HID + k] = bf1(Wg[k * HID + n]);
}

// ---------------------------------------------------------------------------
// K1: xwh = bf16( (x @ W) * dinv[row] )  via MFMA 16x16x32 bf16.
//     PRE-SCALED by dinv so the pull loop is pure adds.
//     64-row tiles, 4 waves; x and W^T staged in XOR-swizzled bf16 LDS.
// ---------------------------------------------------------------------------
__global__ __launch_bounds__(256) void k_gemm(const float* __restrict__ x,
                                              const unsigned short* __restrict__ wt,
                                              const float* __restrict__ dinv,
                                              unsigned short* __restrict__ xwh) {
    __shared__ char sm[49152];  // xs bf16[64][128] @0 (16KB); Wt bf16[128][128] @16384 (32KB)
    const int tid = threadIdx.x;
    const int r0 = blockIdx.x * 64;

    {   // stage W^T: 2048 uint4, 8 per thread, coalesced
        const uint4* w4 = (const uint4*)wt;
#pragma unroll
        for (int i = 0; i < 8; ++i) {
            int f = i * 256 + tid;
            int n = f >> 4;        // row 0..127
            int kq = f & 15;       // 16B chunk
            uint4 v = w4[f];
            *(uint4*)(sm + 16384 + n * 256 + ((kq * 16) ^ ((n & 7) << 4))) = v;
        }
    }
    {   // stage x tile -> bf16: 2048 float4, 8 per thread
        const float4* x4 = (const float4*)x;
#pragma unroll
        for (int i = 0; i < 8; ++i) {
            int f = i * 256 + tid;
            int row = f >> 5;      // 32 float4 per row
            int kq = f & 31;
            int grow = r0 + row;
            float4 gv;
            if (grow < N_NODES) gv = x4[(size_t)grow * 32 + kq];
            else { gv.x = 0.f; gv.y = 0.f; gv.z = 0.f; gv.w = 0.f; }
            uint2 p;
            p.x = pack2(gv.x, gv.y);
            p.y = pack2(gv.z, gv.w);
            *(uint2*)(sm + row * 256 + ((kq * 8) ^ ((row & 7) << 4))) = p;
        }
    }
    __syncthreads();

    const int w = tid >> 6;   // wave id: rows w*16..w*16+15 of tile
    const int l = tid & 63;
    const int lm = l & 15;
    const int g = l >> 4;

    bf16x8 a[4];
#pragma unroll
    for (int kc = 0; kc < 4; ++kc) {
        int row = w * 16 + lm;
        int kb = kc * 64 + g * 16;
        a[kc] = *(const bf16x8*)(sm + row * 256 + (kb ^ ((row & 7) << 4)));
    }

    f32x4 accs[8];
#pragma unroll
    for (int nt = 0; nt < 8; ++nt) accs[nt] = (f32x4){0.f, 0.f, 0.f, 0.f};

#pragma unroll
    for (int nt = 0; nt < 8; ++nt) {
        int n = nt * 16 + lm;
        const char* bp = sm + 16384 + n * 256;
        int msk = (n & 7) << 4;
#pragma unroll
        for (int kc = 0; kc < 4; ++kc) {
            int kb = kc * 64 + g * 16;
            bf16x8 b = *(const bf16x8*)(bp + (kb ^ msk));
            accs[nt] = __builtin_amdgcn_mfma_f32_16x16x32_bf16(a[kc], b, accs[nt], 0, 0, 0);
        }
    }

    float dv[4];
#pragma unroll
    for (int r = 0; r < 4; ++r) {
        int row = r0 + w * 16 + g * 4 + r;
        dv[r] = (row < N_NODES) ? dinv[row] : 0.f;
    }

#pragma unroll
    for (int nt = 0; nt < 8; ++nt) {
        int col = nt * 16 + lm;
#pragma unroll
        for (int r = 0; r < 4; ++r) {
            int row = r0 + w * 16 + g * 4 + r;
            if (row < N_NODES) xwh[(size_t)row * HID + col] = bf1(accs[nt][r] * dv[r]);
        }
    }
}

// ---------------------------------------------------------------------------
// K2: rank pass: rank[e] = count[dst]++ (int atomics; rank write coalesced)
// ---------------------------------------------------------------------------
__global__ void k_rank(const int* __restrict__ ei, int* __restrict__ count,
                       int* __restrict__ rank) {
    int e = blockIdx.x * 256 + threadIdx.x;
    if (e < N_EDGES) rank[e] = atomicAdd(&count[ei[N_EDGES + e]], 1);
}

// ---------------------------------------------------------------------------
// K3: CSR range allocator — buckets disjoint, not globally ordered.
//     Emits seg[n] = {start, deg} as one int2.
// ---------------------------------------------------------------------------
__global__ __launch_bounds__(256) void k_alloc(const int* __restrict__ count,
                                               int2* __restrict__ seg,
                                               float* __restrict__ dinv,
                                               int* __restrict__ total) {
    __shared__ int smem[256];
    __shared__ int base;
    const int t = threadIdx.x;
    const int i = blockIdx.x * 256 + t;
    int c = (i < N_NODES) ? count[i] : 0;
    smem[t] = c;
    __syncthreads();
#pragma unroll
    for (int off = 1; off < 256; off <<= 1) {
        int v = (t >= off) ? smem[t - off] : 0;
        __syncthreads();
        smem[t] += v;
        __syncthreads();
    }
    if (t == 255) base = atomicAdd(total, smem[255]);
    int incl = smem[t];
    __syncthreads();
    if (i < N_NODES) {
        seg[i] = make_int2(base + incl - c, c);
        dinv[i] = rsqrtf((float)(c + 1));
    }
}

// ---------------------------------------------------------------------------
// K4: fill CSR (no atomics): csr[seg[dst].x + rank[e]] = src
//     Non-temporal store: scattered dwords bypass L2 (avoid the ~64B/store
//     dirty-line writeback amplification seen as 107MB WRITE_SIZE).
// ---------------------------------------------------------------------------
__global__ void k_fill(const int* __restrict__ ei, const int2* __restrict__ seg,
                       const int* __restrict__ rank, int* __restrict__ csr) {
    int e = blockIdx.x * 256 + threadIdx.x;
    if (e < N_EDGES) {
        int dst = ei[N_EDGES + e];
        int pos = seg[dst].x + rank[e];
        __builtin_nontemporal_store(ei[e], &csr[pos]);
    }
}

// ---------------------------------------------------------------------------
// K5: pull-aggregate v3. ONE WAVE per node; the wave loads up to 64 csr
//     indices in ONE coalesced 256B load, then __shfl-broadcasts each index
//     (LDS pipe ~30cyc vs L2 ~200cyc) -> 8x-unrolled independent gathers.
//     Messages pre-scaled by dinv[src]; loop is pure adds.
// ---------------------------------------------------------------------------
__global__ __launch_bounds__(256) void k_pull(const unsigned* __restrict__ xwp,
                                              const int2* __restrict__ seg,
                                              const int* __restrict__ csr,
                                              const float* __restrict__ dinv,
                                              const float* __restrict__ b,
                                              unsigned* __restrict__ h16) {
    int gid = blockIdx.x * 256 + threadIdx.x;
    int n = gid >> 6;          // one wave per node
    int c = gid & 63;          // dword lane (2 bf16 cols: 2c, 2c+1)
    if (n >= N_NODES) return;

    float aLo, aHi;
    bf2x(xwp[(size_t)n * 64 + c], aLo, aHi);   // self term (carries dinv[n])

    const int2 sg = seg[n];
    const int beg = sg.x;
    const int deg = sg.y;

    for (int base = 0; base < deg; base += 64) {
        const int cnt = min(64, deg - base);
        int myIdx = (c < cnt) ? csr[beg + base + c] : 0;
        int j = 0;
        for (; j + 8 <= cnt; j += 8) {
            int s0 = __shfl(myIdx, j);
            int s1 = __shfl(myIdx, j + 1);
            int s2 = __shfl(myIdx, j + 2);
            int s3 = __shfl(myIdx, j + 3);
            int s4 = __shfl(myIdx, j + 4);
            int s5 = __shfl(myIdx, j + 5);
            int s6 = __shfl(myIdx, j + 6);
            int s7 = __shfl(myIdx, j + 7);
            unsigned m0 = xwp[(size_t)s0 * 64 + c];
            unsigned m1 = xwp[(size_t)s1 * 64 + c];
            unsigned m2 = xwp[(size_t)s2 * 64 + c];
            unsigned m3 = xwp[(size_t)s3 * 64 + c];
            unsigned m4 = xwp[(size_t)s4 * 64 + c];
            unsigned m5 = xwp[(size_t)s5 * 64 + c];
            unsigned m6 = xwp[(size_t)s6 * 64 + c];
            unsigned m7 = xwp[(size_t)s7 * 64 + c];
            float lo, hi;
            bf2x(m0, lo, hi); aLo += lo; aHi += hi;
            bf2x(m1, lo, hi); aLo += lo; aHi += hi;
            bf2x(m2, lo, hi); aLo += lo; aHi += hi;
            bf2x(m3, lo, hi); aLo += lo; aHi += hi;
            bf2x(m4, lo, hi); aLo += lo; aHi += hi;
            bf2x(m5, lo, hi); aLo += lo; aHi += hi;
            bf2x(m6, lo, hi); aLo += lo; aHi += hi;
            bf2x(m7, lo, hi); aLo += lo; aHi += hi;
        }
        for (; j < cnt; ++j) {
            int s = __shfl(myIdx, j);
            unsigned m = xwp[(size_t)s * 64 + c];
            float lo, hi;
            bf2x(m, lo, hi); aLo += lo; aHi += hi;
        }
    }

    float di = dinv[n];
    float2 bv = ((const float2*)b)[c];
    h16[(size_t)n * 64 + c] = pack2(aLo * di + bv.x, aHi * di + bv.y);
}

// ---------------------------------------------------------------------------
// K6: link head. 32 lanes per label edge; W_lin rows in registers.
// ---------------------------------------------------------------------------
__global__ __launch_bounds__(256) void k_link(const int* __restrict__ eli,
                                              const uint4* __restrict__ h16,
                                              const float* __restrict__ Wg,
                                              const float* __restrict__ bl,
                                              float* __restrict__ out) {
    __shared__ float Wl[2 * HID * OUT];
    __shared__ float bls[OUT];
    const int tid = threadIdx.x;
    for (int i = tid; i < 2 * HID * OUT; i += 256) Wl[i] = Wg[i];
    if (tid < OUT) bls[tid] = bl[tid];
    __syncthreads();

    const int lane = tid & 31;
    const int half = lane >> 4;
    const int q = lane & 15;
    float w[8][OUT];
    const int rbase = half * HID + q * 8;
#pragma unroll
    for (int j = 0; j < 8; ++j)
#pragma unroll
        for (int o = 0; o < OUT; ++o) w[j][o] = Wl[(rbase + j) * OUT + o];

    const int grp = (blockIdx.x * 256 + tid) >> 5;
    const int ngrp = gridDim.x * 8;

    for (int l = grp; l < N_LABEL; l += ngrp) {
        int idx = eli[half * N_LABEL + l];
        uint4 hv = h16[(size_t)idx * 16 + q];
        float f[8];
        bf2x(hv.x, f[0], f[1]);
        bf2x(hv.y, f[2], f[3]);
        bf2x(hv.z, f[4], f[5]);
        bf2x(hv.w, f[6], f[7]);

        float acc[OUT] = {0.f, 0.f, 0.f, 0.f, 0.f};
#pragma unroll
        for (int j = 0; j < 8; ++j)
#pragma unroll
            for (int o = 0; o < OUT; ++o) acc[o] += f[j] * w[j][o];

#pragma unroll
        for (int o = 0; o < OUT; ++o) {
            float a = acc[o];
#pragma unroll
            for (int off = 1; off <= 16; off <<= 1) a += __shfl_xor(a, off);
            acc[o] = a;
        }
        if (lane == 0) {
#pragma unroll
            for (int o = 0; o < OUT; ++o) out[(size_t)l * OUT + o] = acc[o] + bls[o];
        }
    }
}

// ---------------------------------------------------------------------------
extern "C" void kernel_launch(void* const* d_in, const int* in_sizes, int n_in,
                              void* d_out, int out_size, void* d_ws, size_t ws_size,
                              hipStream_t stream) {
    const float* x     = (const float*)d_in[0];
    const int*   ei    = (const int*)d_in[1];
    const int*   eli   = (const int*)d_in[2];
    const float* W_gcn = (const float*)d_in[3];
    const float* b_gcn = (const float*)d_in[4];
    const float* W_lin = (const float*)d_in[5];
    const float* b_lin = (const float*)d_in[6];
    float* out = (float*)d_out;

    // workspace layout
    unsigned short* xwh = (unsigned short*)d_ws;               // 12.8M u16 (25.6 MB), pre-scaled by dinv
    unsigned short* h16 = xwh + (size_t)N_NODES * HID;         // 12.8M u16 (25.6 MB)
    float* dinv      = (float*)(h16 + (size_t)N_NODES * HID);  // 100k f32
    int*   count     = (int*)(dinv + N_NODES);                 // 100k int
    int*   rank      = count + N_NODES;                        // 1.6M int
    int2*  seg       = (int2*)(rank + N_EDGES);                // 100k int2
    int*   total     = (int*)(seg + N_NODES);                  // 1 int (+3 pad)
    unsigned short* wt = (unsigned short*)(total + 4);         // 16384 u16 (32KB)
    int*   csr       = (int*)(wt + HID * HID);                 // 1.6M int

    hipMemsetAsync(count, 0, N_NODES * sizeof(int), stream);
    hipMemsetAsync(total, 0, sizeof(int), stream);

    // K0: W^T -> bf16
    k_prep<<<HID, HID, 0, stream>>>(W_gcn, wt);
    // K2: in-degree count + per-edge rank  (before gemm: gemm needs dinv)
    k_rank<<<(N_EDGES + 255) / 256, 256, 0, stream>>>(ei, count, rank);
    // K3: CSR range allocation (seg = {start,deg}) + dinv
    k_alloc<<<(N_NODES + 255) / 256, 256, 0, stream>>>(count, seg, dinv, total);
    // K1: xwh = bf16((x @ W_gcn) * dinv) via MFMA
    k_gemm<<<(N_NODES + 63) / 64, 256, 0, stream>>>(x, wt, dinv, xwh);
    // K4: CSR fill (atomic-free, non-temporal stores)
    k_fill<<<(N_EDGES + 255) / 256, 256, 0, stream>>>(ei, seg, rank, csr);
    // K5: pull aggregation (1 wave/node, shfl-broadcast indices, 8x MLP)
    k_pull<<<(int)(((size_t)N_NODES * 64 + 255) / 256), 256, 0, stream>>>(
        (const unsigned*)xwh, seg, csr, dinv, b_gcn, (unsigned*)h16);
    // K6: link prediction head
    k_link<<<2048, 256, 0, stream>>>(eli, (const uint4*)h16, W_lin, b_lin, out);
}

// Round 8
// 252.979 us; speedup vs baseline: 1.0613x; 1.0613x over previous
//
#include <hip/hip_runtime.h>

#define N_NODES 100000
#define N_EDGES 1600000
#define N_LABEL 200000
#define HID 128
#define OUT 5

typedef __attribute__((ext_vector_type(8))) short bf16x8;
typedef __attribute__((ext_vector_type(4))) float f32x4;

// ---- bf16 helpers (manual, RNE) -------------------------------------------
__device__ inline void bf2x(unsigned u, float& lo, float& hi) {
    lo = __uint_as_float(u << 16);
    hi = __uint_as_float(u & 0xffff0000u);
}
__device__ inline unsigned pack2(float a, float b) {
    unsigned ua = __float_as_uint(a), ub = __float_as_uint(b);
    ua = (ua + 0x7fffu + ((ua >> 16) & 1u)) >> 16;
    ub = (ub + 0x7fffu + ((ub >> 16) & 1u)) & 0xffff0000u;
    return ua | ub;
}
__device__ inline unsigned short bf1(float f) {
    unsigned u = __float_as_uint(f);
    return (unsigned short)((u + 0x7fffu + ((u >> 16) & 1u)) >> 16);
}

// ---------------------------------------------------------------------------
// K0: wt[n][k] = bf16(W[k][n])  (transpose + convert, one-time 64KB)
// ---------------------------------------------------------------------------
__global__ void k_prep(const float* __restrict__ Wg, unsigned short* __restrict__ wt) {
    int n = blockIdx.x;   // 128 blocks
    int k = threadIdx.x;  // 128 threads
    wt[n * HID + k] = bf1(Wg[k * HID + n]);
}

// ---------------------------------------------------------------------------
// K1: xwh = bf16( (x @ W) * dinv[row] )  via MFMA 16x16x32 bf16.
//     PRE-SCALED by dinv so the pull loop is pure adds.
//     64-row tiles, 4 waves; x and W^T staged in XOR-swizzled bf16 LDS.
// ---------------------------------------------------------------------------
__global__ __launch_bounds__(256) void k_gemm(const float* __restrict__ x,
                                              const unsigned short* __restrict__ wt,
                                              const float* __restrict__ dinv,
                                              unsigned short* __restrict__ xwh) {
    __shared__ char sm[49152];  // xs bf16[64][128] @0 (16KB); Wt bf16[128][128] @16384 (32KB)
    const int tid = threadIdx.x;
    const int r0 = blockIdx.x * 64;

    {   // stage W^T: 2048 uint4, 8 per thread, coalesced
        const uint4* w4 = (const uint4*)wt;
#pragma unroll
        for (int i = 0; i < 8; ++i) {
            int f = i * 256 + tid;
            int n = f >> 4;        // row 0..127
            int kq = f & 15;       // 16B chunk
            uint4 v = w4[f];
            *(uint4*)(sm + 16384 + n * 256 + ((kq * 16) ^ ((n & 7) << 4))) = v;
        }
    }
    {   // stage x tile -> bf16: 2048 float4, 8 per thread
        const float4* x4 = (const float4*)x;
#pragma unroll
        for (int i = 0; i < 8; ++i) {
            int f = i * 256 + tid;
            int row = f >> 5;      // 32 float4 per row
            int kq = f & 31;
            int grow = r0 + row;
            float4 gv;
            if (grow < N_NODES) gv = x4[(size_t)grow * 32 + kq];
            else { gv.x = 0.f; gv.y = 0.f; gv.z = 0.f; gv.w = 0.f; }
            uint2 p;
            p.x = pack2(gv.x, gv.y);
            p.y = pack2(gv.z, gv.w);
            *(uint2*)(sm + row * 256 + ((kq * 8) ^ ((row & 7) << 4))) = p;
        }
    }
    __syncthreads();

    const int w = tid >> 6;   // wave id: rows w*16..w*16+15 of tile
    const int l = tid & 63;
    const int lm = l & 15;
    const int g = l >> 4;

    bf16x8 a[4];
#pragma unroll
    for (int kc = 0; kc < 4; ++kc) {
        int row = w * 16 + lm;
        int kb = kc * 64 + g * 16;
        a[kc] = *(const bf16x8*)(sm + row * 256 + (kb ^ ((row & 7) << 4)));
    }

    f32x4 accs[8];
#pragma unroll
    for (int nt = 0; nt < 8; ++nt) accs[nt] = (f32x4){0.f, 0.f, 0.f, 0.f};

#pragma unroll
    for (int nt = 0; nt < 8; ++nt) {
        int n = nt * 16 + lm;
        const char* bp = sm + 16384 + n * 256;
        int msk = (n & 7) << 4;
#pragma unroll
        for (int kc = 0; kc < 4; ++kc) {
            int kb = kc * 64 + g * 16;
            bf16x8 b = *(const bf16x8*)(bp + (kb ^ msk));
            accs[nt] = __builtin_amdgcn_mfma_f32_16x16x32_bf16(a[kc], b, accs[nt], 0, 0, 0);
        }
    }

    float dv[4];
#pragma unroll
    for (int r = 0; r < 4; ++r) {
        int row = r0 + w * 16 + g * 4 + r;
        dv[r] = (row < N_NODES) ? dinv[row] : 0.f;
    }

#pragma unroll
    for (int nt = 0; nt < 8; ++nt) {
        int col = nt * 16 + lm;
#pragma unroll
        for (int r = 0; r < 4; ++r) {
            int row = r0 + w * 16 + g * 4 + r;
            if (row < N_NODES) xwh[(size_t)row * HID + col] = bf1(accs[nt][r] * dv[r]);
        }
    }
}

// ---------------------------------------------------------------------------
// K2: rank pass, 8 edges/thread (strided, coalesced): 8 independent
//     atomic-with-return ops in flight per thread -> latency hiding via MLP.
//     Launch exactly N_EDGES/8 threads.
// ---------------------------------------------------------------------------
#define RANK_T (N_EDGES / 8)   // 200000 threads
__global__ void k_rank(const int* __restrict__ ei, int* __restrict__ count,
                       int* __restrict__ rank) {
    int t = blockIdx.x * 256 + threadIdx.x;
    if (t >= RANK_T) return;
    int d[8];
#pragma unroll
    for (int i = 0; i < 8; ++i) d[i] = ei[N_EDGES + t + i * RANK_T];
    int r[8];
#pragma unroll
    for (int i = 0; i < 8; ++i) r[i] = atomicAdd(&count[d[i]], 1);
#pragma unroll
    for (int i = 0; i < 8; ++i) rank[t + i * RANK_T] = r[i];
}

// ---------------------------------------------------------------------------
// K3: CSR range allocator — buckets disjoint, not globally ordered.
//     Emits seg[n] = {start, deg} as one int2.
// ---------------------------------------------------------------------------
__global__ __launch_bounds__(256) void k_alloc(const int* __restrict__ count,
                                               int2* __restrict__ seg,
                                               float* __restrict__ dinv,
                                               int* __restrict__ total) {
    __shared__ int smem[256];
    __shared__ int base;
    const int t = threadIdx.x;
    const int i = blockIdx.x * 256 + t;
    int c = (i < N_NODES) ? count[i] : 0;
    smem[t] = c;
    __syncthreads();
#pragma unroll
    for (int off = 1; off < 256; off <<= 1) {
        int v = (t >= off) ? smem[t - off] : 0;
        __syncthreads();
        smem[t] += v;
        __syncthreads();
    }
    if (t == 255) base = atomicAdd(total, smem[255]);
    int incl = smem[t];
    __syncthreads();
    if (i < N_NODES) {
        seg[i] = make_int2(base + incl - c, c);
        dinv[i] = rsqrtf((float)(c + 1));
    }
}

// ---------------------------------------------------------------------------
// K4: fill CSR (no atomics), 8 edges/thread for MLP:
//     csr[seg[dst].x + rank[e]] = src   (normal stores; L2 absorbs)
// ---------------------------------------------------------------------------
__global__ void k_fill(const int* __restrict__ ei, const int2* __restrict__ seg,
                       const int* __restrict__ rank, int* __restrict__ csr) {
    int t = blockIdx.x * 256 + threadIdx.x;
    if (t >= RANK_T) return;
    int d[8], s[8], r[8];
#pragma unroll
    for (int i = 0; i < 8; ++i) d[i] = ei[N_EDGES + t + i * RANK_T];
#pragma unroll
    for (int i = 0; i < 8; ++i) s[i] = ei[t + i * RANK_T];
#pragma unroll
    for (int i = 0; i < 8; ++i) r[i] = rank[t + i * RANK_T];
    int pos[8];
#pragma unroll
    for (int i = 0; i < 8; ++i) pos[i] = seg[d[i]].x + r[i];
#pragma unroll
    for (int i = 0; i < 8; ++i) csr[pos[i]] = s[i];
}

// ---------------------------------------------------------------------------
// K5: pull-aggregate v3. ONE WAVE per node; wave loads up to 64 csr indices
//     in ONE coalesced 256B load, __shfl-broadcasts each index, 8x-unrolled
//     independent gathers. Messages pre-scaled by dinv[src]; pure adds.
// ---------------------------------------------------------------------------
__global__ __launch_bounds__(256) void k_pull(const unsigned* __restrict__ xwp,
                                              const int2* __restrict__ seg,
                                              const int* __restrict__ csr,
                                              const float* __restrict__ dinv,
                                              const float* __restrict__ b,
                                              unsigned* __restrict__ h16) {
    int gid = blockIdx.x * 256 + threadIdx.x;
    int n = gid >> 6;          // one wave per node
    int c = gid & 63;          // dword lane (2 bf16 cols: 2c, 2c+1)
    if (n >= N_NODES) return;

    float aLo, aHi;
    bf2x(xwp[(size_t)n * 64 + c], aLo, aHi);   // self term (carries dinv[n])

    const int2 sg = seg[n];
    const int beg = sg.x;
    const int deg = sg.y;

    for (int base = 0; base < deg; base += 64) {
        const int cnt = min(64, deg - base);
        int myIdx = (c < cnt) ? csr[beg + base + c] : 0;
        int j = 0;
        for (; j + 8 <= cnt; j += 8) {
            int s0 = __shfl(myIdx, j);
            int s1 = __shfl(myIdx, j + 1);
            int s2 = __shfl(myIdx, j + 2);
            int s3 = __shfl(myIdx, j + 3);
            int s4 = __shfl(myIdx, j + 4);
            int s5 = __shfl(myIdx, j + 5);
            int s6 = __shfl(myIdx, j + 6);
            int s7 = __shfl(myIdx, j + 7);
            unsigned m0 = xwp[(size_t)s0 * 64 + c];
            unsigned m1 = xwp[(size_t)s1 * 64 + c];
            unsigned m2 = xwp[(size_t)s2 * 64 + c];
            unsigned m3 = xwp[(size_t)s3 * 64 + c];
            unsigned m4 = xwp[(size_t)s4 * 64 + c];
            unsigned m5 = xwp[(size_t)s5 * 64 + c];
            unsigned m6 = xwp[(size_t)s6 * 64 + c];
            unsigned m7 = xwp[(size_t)s7 * 64 + c];
            float lo, hi;
            bf2x(m0, lo, hi); aLo += lo; aHi += hi;
            bf2x(m1, lo, hi); aLo += lo; aHi += hi;
            bf2x(m2, lo, hi); aLo += lo; aHi += hi;
            bf2x(m3, lo, hi); aLo += lo; aHi += hi;
            bf2x(m4, lo, hi); aLo += lo; aHi += hi;
            bf2x(m5, lo, hi); aLo += lo; aHi += hi;
            bf2x(m6, lo, hi); aLo += lo; aHi += hi;
            bf2x(m7, lo, hi); aLo += lo; aHi += hi;
        }
        for (; j < cnt; ++j) {
            int s = __shfl(myIdx, j);
            unsigned m = xwp[(size_t)s * 64 + c];
            float lo, hi;
            bf2x(m, lo, hi); aLo += lo; aHi += hi;
        }
    }

    float di = dinv[n];
    float2 bv = ((const float2*)b)[c];
    h16[(size_t)n * 64 + c] = pack2(aLo * di + bv.x, aHi * di + bv.y);
}

// ---------------------------------------------------------------------------
// K6: link head. 32 lanes per label edge; W_lin rows in registers;
//     2-edge unroll per group -> 2 independent 32B gathers in flight.
// ---------------------------------------------------------------------------
__global__ __launch_bounds__(256) void k_link(const int* __restrict__ eli,
                                              const uint4* __restrict__ h16,
                                              const float* __restrict__ Wg,
                                              const float* __restrict__ bl,
                                              float* __restrict__ out) {
    __shared__ float Wl[2 * HID * OUT];
    __shared__ float bls[OUT];
    const int tid = threadIdx.x;
    for (int i = tid; i < 2 * HID * OUT; i += 256) Wl[i] = Wg[i];
    if (tid < OUT) bls[tid] = bl[tid];
    __syncthreads();

    const int lane = tid & 31;
    const int half = lane >> 4;
    const int q = lane & 15;
    float w[8][OUT];
    const int rbase = half * HID + q * 8;
#pragma unroll
    for (int j = 0; j < 8; ++j)
#pragma unroll
        for (int o = 0; o < OUT; ++o) w[j][o] = Wl[(rbase + j) * OUT + o];

    const int grp = (blockIdx.x * 256 + tid) >> 5;
    const int ngrp = gridDim.x * 8;

    for (int l0 = grp; l0 < N_LABEL; l0 += 2 * ngrp) {
        const int l1 = l0 + ngrp;
        const bool has1 = (l1 < N_LABEL);

        int idx0 = eli[half * N_LABEL + l0];
        int idx1 = has1 ? eli[half * N_LABEL + l1] : idx0;
        uint4 hv0 = h16[(size_t)idx0 * 16 + q];
        uint4 hv1 = h16[(size_t)idx1 * 16 + q];

        float f0[8], f1[8];
        bf2x(hv0.x, f0[0], f0[1]); bf2x(hv0.y, f0[2], f0[3]);
        bf2x(hv0.z, f0[4], f0[5]); bf2x(hv0.w, f0[6], f0[7]);
        bf2x(hv1.x, f1[0], f1[1]); bf2x(hv1.y, f1[2], f1[3]);
        bf2x(hv1.z, f1[4], f1[5]); bf2x(hv1.w, f1[6], f1[7]);

        float a0[OUT] = {0.f, 0.f, 0.f, 0.f, 0.f};
        float a1[OUT] = {0.f, 0.f, 0.f, 0.f, 0.f};
#pragma unroll
        for (int j = 0; j < 8; ++j)
#pragma unroll
            for (int o = 0; o < OUT; ++o) {
                a0[o] += f0[j] * w[j][o];
                a1[o] += f1[j] * w[j][o];
            }

#pragma unroll
        for (int o = 0; o < OUT; ++o) {
            float v0 = a0[o], v1 = a1[o];
#pragma unroll
            for (int off = 1; off <= 16; off <<= 1) {
                v0 += __shfl_xor(v0, off);
                v1 += __shfl_xor(v1, off);
            }
            a0[o] = v0; a1[o] = v1;
        }
        if (lane == 0) {
#pragma unroll
            for (int o = 0; o < OUT; ++o) out[(size_t)l0 * OUT + o] = a0[o] + bls[o];
            if (has1) {
#pragma unroll
                for (int o = 0; o < OUT; ++o) out[(size_t)l1 * OUT + o] = a1[o] + bls[o];
            }
        }
    }
}

// ---------------------------------------------------------------------------
extern "C" void kernel_launch(void* const* d_in, const int* in_sizes, int n_in,
                              void* d_out, int out_size, void* d_ws, size_t ws_size,
                              hipStream_t stream) {
    const float* x     = (const float*)d_in[0];
    const int*   ei    = (const int*)d_in[1];
    const int*   eli   = (const int*)d_in[2];
    const float* W_gcn = (const float*)d_in[3];
    const float* b_gcn = (const float*)d_in[4];
    const float* W_lin = (const float*)d_in[5];
    const float* b_lin = (const float*)d_in[6];
    float* out = (float*)d_out;

    // workspace layout
    unsigned short* xwh = (unsigned short*)d_ws;               // 12.8M u16 (25.6 MB), pre-scaled by dinv
    unsigned short* h16 = xwh + (size_t)N_NODES * HID;         // 12.8M u16 (25.6 MB)
    float* dinv      = (float*)(h16 + (size_t)N_NODES * HID);  // 100k f32
    int*   count     = (int*)(dinv + N_NODES);                 // 100k int
    int*   rank      = count + N_NODES;                        // 1.6M int
    int2*  seg       = (int2*)(rank + N_EDGES);                // 100k int2
    int*   total     = (int*)(seg + N_NODES);                  // 1 int (+3 pad)
    unsigned short* wt = (unsigned short*)(total + 4);         // 16384 u16 (32KB)
    int*   csr       = (int*)(wt + HID * HID);                 // 1.6M int

    hipMemsetAsync(count, 0, N_NODES * sizeof(int), stream);
    hipMemsetAsync(total, 0, sizeof(int), stream);

    // K0: W^T -> bf16
    k_prep<<<HID, HID, 0, stream>>>(W_gcn, wt);
    // K2: in-degree count + per-edge rank (8 edges/thread)
    k_rank<<<(RANK_T + 255) / 256, 256, 0, stream>>>(ei, count, rank);
    // K3: CSR range allocation (seg = {start,deg}) + dinv
    k_alloc<<<(N_NODES + 255) / 256, 256, 0, stream>>>(count, seg, dinv, total);
    // K1: xwh = bf16((x @ W_gcn) * dinv) via MFMA
    k_gemm<<<(N_NODES + 63) / 64, 256, 0, stream>>>(x, wt, dinv, xwh);
    // K4: CSR fill (atomic-free, 8 edges/thread)
    k_fill<<<(RANK_T + 255) / 256, 256, 0, stream>>>(ei, seg, rank, csr);
    // K5: pull aggregation (1 wave/node, shfl-broadcast indices, 8x MLP)
    k_pull<<<(int)(((size_t)N_NODES * 64 + 255) / 256), 256, 0, stream>>>(
        (const unsigned*)xwh, seg, csr, dinv, b_gcn, (unsigned*)h16);
    // K6: link prediction head (2-edge unroll)
    k_link<<<2048, 256, 0, stream>>>(eli, (const uint4*)h16, W_lin, b_lin, out);
}

// Round 9
// 168.940 us; speedup vs baseline: 1.5892x; 1.4975x over previous
//
#include <hip/hip_runtime.h>

#define N_NODES 100000
#define N_EDGES 1600000
#define N_LABEL 200000
#define HID 128
#define OUT 5

#define NBUCK 391        // ceil(N_NODES/256)
#define EPB   2048       // edges per partition block
#define NBLK_E 782       // ceil(N_EDGES/EPB)

typedef __attribute__((ext_vector_type(8))) short bf16x8;
typedef __attribute__((ext_vector_type(4))) float f32x4;

// ---- bf16 helpers (manual, RNE) -------------------------------------------
__device__ inline void bf2x(unsigned u, float& lo, float& hi) {
    lo = __uint_as_float(u << 16);
    hi = __uint_as_float(u & 0xffff0000u);
}
__device__ inline unsigned pack2(float a, float b) {
    unsigned ua = __float_as_uint(a), ub = __float_as_uint(b);
    ua = (ua + 0x7fffu + ((ua >> 16) & 1u)) >> 16;
    ub = (ub + 0x7fffu + ((ub >> 16) & 1u)) & 0xffff0000u;
    return ua | ub;
}
__device__ inline unsigned short bf1(float f) {
    unsigned u = __float_as_uint(f);
    return (unsigned short)((u + 0x7fffu + ((u >> 16) & 1u)) >> 16);
}

// ---------------------------------------------------------------------------
// K0a: wt[n][k] = bf16(W_gcn[k][n])
// ---------------------------------------------------------------------------
__global__ void k_prep(const float* __restrict__ Wg, unsigned short* __restrict__ wt) {
    int n = blockIdx.x;   // 128
    int k = threadIdx.x;  // 128
    wt[n * HID + k] = bf1(Wg[k * HID + n]);
}

// K0b: w2t[j][k] = bf16(W_lin[k][j]) (j<5: top half) / bf16(W_lin[128+k][j-5]) (5<=j<10) / 0
__global__ void k_prep2(const float* __restrict__ Wl, unsigned short* __restrict__ w2t) {
    int j = blockIdx.x;   // 16
    int k = threadIdx.x;  // 128
    float v = 0.f;
    if (j < OUT) v = Wl[k * OUT + j];
    else if (j < 2 * OUT) v = Wl[(HID + k) * OUT + (j - OUT)];
    w2t[j * HID + k] = bf1(v);
}

// ---------------------------------------------------------------------------
// CSR build, atomic-free (global). Buckets = node>>8 (391 buckets x 256 nodes).
// ---------------------------------------------------------------------------
// A: per-(block,bucket) histogram via LDS atomics
__global__ __launch_bounds__(256) void k_hist(const int* __restrict__ ei,
                                              int* __restrict__ hist) {
    __shared__ int h[NBUCK];
    const int t = threadIdx.x, b = blockIdx.x;
    for (int i = t; i < NBUCK; i += 256) h[i] = 0;
    __syncthreads();
    const int e0 = b * EPB;
#pragma unroll
    for (int i = 0; i < 8; ++i) {
        int e = e0 + i * 256 + t;
        if (e < N_EDGES) atomicAdd(&h[ei[N_EDGES + e] >> 8], 1);
    }
    __syncthreads();
    for (int i = t; i < NBUCK; i += 256) hist[i * NBLK_E + b] = h[i];
}

// B: in-place exclusive scan of each bucket row over its 782 block entries
__global__ __launch_bounds__(256) void k_scanb(int* __restrict__ hist,
                                               int* __restrict__ btot) {
    __shared__ int part[256];
    const int b = blockIdx.x, t = threadIdx.x;
    int* row = hist + b * NBLK_E;
    const int lo = t * 4, hi = min(lo + 4, NBLK_E);
    int v[4]; int s = 0;
    for (int i = lo; i < hi; ++i) { v[i - lo] = row[i]; s += v[i - lo]; }
    part[t] = s;
    __syncthreads();
#pragma unroll
    for (int off = 1; off < 256; off <<= 1) {
        int a = (t >= off) ? part[t - off] : 0;
        __syncthreads();
        part[t] += a;
        __syncthreads();
    }
    int run = part[t] - s;
    for (int i = lo; i < hi; ++i) { int x = v[i - lo]; row[i] = run; run += x; }
    if (t == 255) btot[b] = part[255];
}

// B2: bucket base = exclusive scan of 391 totals (1 block)
__global__ __launch_bounds__(512) void k_base(const int* __restrict__ btot,
                                              int* __restrict__ bbase) {
    __shared__ int part[512];
    const int t = threadIdx.x;
    int v = (t < NBUCK) ? btot[t] : 0;
    part[t] = v;
    __syncthreads();
#pragma unroll
    for (int off = 1; off < 512; off <<= 1) {
        int a = (t >= off) ? part[t - off] : 0;
        __syncthreads();
        part[t] += a;
        __syncthreads();
    }
    if (t < NBUCK) bbase[t] = part[t] - v;
    if (t == 511) bbase[NBUCK] = part[511];
}

// C: partition edges into bucket regions (LDS cursors, deterministic ranges)
__global__ __launch_bounds__(256) void k_part(const int* __restrict__ ei,
                                              const int* __restrict__ hist,
                                              const int* __restrict__ bbase,
                                              int2* __restrict__ bedge) {
    __shared__ int cur[NBUCK];
    const int t = threadIdx.x, b = blockIdx.x;
    for (int i = t; i < NBUCK; i += 256) cur[i] = bbase[i] + hist[i * NBLK_E + b];
    __syncthreads();
    const int e0 = b * EPB;
#pragma unroll
    for (int i = 0; i < 8; ++i) {
        int e = e0 + i * 256 + t;
        if (e < N_EDGES) {
            int dst = ei[N_EDGES + e];
            int src = ei[e];
            int pos = atomicAdd(&cur[dst >> 8], 1);
            bedge[pos] = make_int2(src, dst & 255);
        }
    }
}

// D: per-bucket CSR build: LDS count + scan + rank -> csr, seg, dinv
__global__ __launch_bounds__(256) void k_build(const int2* __restrict__ bedge,
                                               const int* __restrict__ bbase,
                                               int* __restrict__ csr,
                                               int2* __restrict__ seg,
                                               float* __restrict__ dinv) {
    __shared__ int cnt[256];
    __shared__ int nb[256];
    __shared__ int cursor[256];
    const int b = blockIdx.x, t = threadIdx.x;
    const int base = bbase[b];
    const int size = bbase[b + 1] - base;
    cnt[t] = 0;
    __syncthreads();
    for (int i = t; i < size; i += 256) atomicAdd(&cnt[bedge[base + i].y], 1);
    __syncthreads();
    const int c = cnt[t];
    nb[t] = c;
    __syncthreads();
#pragma unroll
    for (int off = 1; off < 256; off <<= 1) {
        int a = (t >= off) ? nb[t - off] : 0;
        __syncthreads();
        nb[t] += a;
        __syncthreads();
    }
    const int myBase = nb[t] - c;
    cursor[t] = myBase;
    __syncthreads();
    for (int i = t; i < size; i += 256) {
        int2 ed = bedge[base + i];
        int pos = atomicAdd(&cursor[ed.y], 1);
        csr[base + pos] = ed.x;
    }
    const int n = b * 256 + t;
    if (n < N_NODES) {
        seg[n] = make_int2(base + myBase, c);
        dinv[n] = rsqrtf((float)(c + 1));
    }
}

// ---------------------------------------------------------------------------
// K1: xwh = bf16( (x @ W) * dinv[row] )  via MFMA 16x16x32 bf16.
// ---------------------------------------------------------------------------
__global__ __launch_bounds__(256) void k_gemm(const float* __restrict__ x,
                                              const unsigned short* __restrict__ wt,
                                              const float* __restrict__ dinv,
                                              unsigned short* __restrict__ xwh) {
    __shared__ char sm[49152];  // xs bf16[64][128] @0; Wt bf16[128][128] @16384
    const int tid = threadIdx.x;
    const int r0 = blockIdx.x * 64;

    {   // stage W^T
        const uint4* w4 = (const uint4*)wt;
#pragma unroll
        for (int i = 0; i < 8; ++i) {
            int f = i * 256 + tid;
            int n = f >> 4;
            int kq = f & 15;
            uint4 v = w4[f];
            *(uint4*)(sm + 16384 + n * 256 + ((kq * 16) ^ ((n & 7) << 4))) = v;
        }
    }
    {   // stage x tile -> bf16
        const float4* x4 = (const float4*)x;
#pragma unroll
        for (int i = 0; i < 8; ++i) {
            int f = i * 256 + tid;
            int row = f >> 5;
            int kq = f & 31;
            int grow = r0 + row;
            float4 gv;
            if (grow < N_NODES) gv = x4[(size_t)grow * 32 + kq];
            else { gv.x = 0.f; gv.y = 0.f; gv.z = 0.f; gv.w = 0.f; }
            uint2 p;
            p.x = pack2(gv.x, gv.y);
            p.y = pack2(gv.z, gv.w);
            *(uint2*)(sm + row * 256 + ((kq * 8) ^ ((row & 7) << 4))) = p;
        }
    }
    __syncthreads();

    const int w = tid >> 6;
    const int l = tid & 63;
    const int lm = l & 15;
    const int g = l >> 4;

    bf16x8 a[4];
#pragma unroll
    for (int kc = 0; kc < 4; ++kc) {
        int row = w * 16 + lm;
        int kb = kc * 64 + g * 16;
        a[kc] = *(const bf16x8*)(sm + row * 256 + (kb ^ ((row & 7) << 4)));
    }

    f32x4 accs[8];
#pragma unroll
    for (int nt = 0; nt < 8; ++nt) accs[nt] = (f32x4){0.f, 0.f, 0.f, 0.f};

#pragma unroll
    for (int nt = 0; nt < 8; ++nt) {
        int n = nt * 16 + lm;
        const char* bp = sm + 16384 + n * 256;
        int msk = (n & 7) << 4;
#pragma unroll
        for (int kc = 0; kc < 4; ++kc) {
            int kb = kc * 64 + g * 16;
            bf16x8 b = *(const bf16x8*)(bp + (kb ^ msk));
            accs[nt] = __builtin_amdgcn_mfma_f32_16x16x32_bf16(a[kc], b, accs[nt], 0, 0, 0);
        }
    }

    float dv[4];
#pragma unroll
    for (int r = 0; r < 4; ++r) {
        int row = r0 + w * 16 + g * 4 + r;
        dv[r] = (row < N_NODES) ? dinv[row] : 0.f;
    }

#pragma unroll
    for (int nt = 0; nt < 8; ++nt) {
        int col = nt * 16 + lm;
#pragma unroll
        for (int r = 0; r < 4; ++r) {
            int row = r0 + w * 16 + g * 4 + r;
            if (row < N_NODES) xwh[(size_t)row * HID + col] = bf1(accs[nt][r] * dv[r]);
        }
    }
}

// ---------------------------------------------------------------------------
// K5: pull-aggregate. One wave/node; coalesced csr load + shfl broadcast;
//     8x-unrolled independent gathers. Messages pre-scaled by dinv[src].
// ---------------------------------------------------------------------------
__global__ __launch_bounds__(256) void k_pull(const unsigned* __restrict__ xwp,
                                              const int2* __restrict__ seg,
                                              const int* __restrict__ csr,
                                              const float* __restrict__ dinv,
                                              const float* __restrict__ b,
                                              unsigned* __restrict__ h16) {
    int gid = blockIdx.x * 256 + threadIdx.x;
    int n = gid >> 6;
    int c = gid & 63;
    if (n >= N_NODES) return;

    float aLo, aHi;
    bf2x(xwp[(size_t)n * 64 + c], aLo, aHi);   // self term (carries dinv[n])

    const int2 sg = seg[n];
    const int beg = sg.x;
    const int deg = sg.y;

    for (int base = 0; base < deg; base += 64) {
        const int cnt = min(64, deg - base);
        int myIdx = (c < cnt) ? csr[beg + base + c] : 0;
        int j = 0;
        for (; j + 8 <= cnt; j += 8) {
            int s0 = __shfl(myIdx, j);
            int s1 = __shfl(myIdx, j + 1);
            int s2 = __shfl(myIdx, j + 2);
            int s3 = __shfl(myIdx, j + 3);
            int s4 = __shfl(myIdx, j + 4);
            int s5 = __shfl(myIdx, j + 5);
            int s6 = __shfl(myIdx, j + 6);
            int s7 = __shfl(myIdx, j + 7);
            unsigned m0 = xwp[(size_t)s0 * 64 + c];
            unsigned m1 = xwp[(size_t)s1 * 64 + c];
            unsigned m2 = xwp[(size_t)s2 * 64 + c];
            unsigned m3 = xwp[(size_t)s3 * 64 + c];
            unsigned m4 = xwp[(size_t)s4 * 64 + c];
            unsigned m5 = xwp[(size_t)s5 * 64 + c];
            unsigned m6 = xwp[(size_t)s6 * 64 + c];
            unsigned m7 = xwp[(size_t)s7 * 64 + c];
            float lo, hi;
            bf2x(m0, lo, hi); aLo += lo; aHi += hi;
            bf2x(m1, lo, hi); aLo += lo; aHi += hi;
            bf2x(m2, lo, hi); aLo += lo; aHi += hi;
            bf2x(m3, lo, hi); aLo += lo; aHi += hi;
            bf2x(m4, lo, hi); aLo += lo; aHi += hi;
            bf2x(m5, lo, hi); aLo += lo; aHi += hi;
            bf2x(m6, lo, hi); aLo += lo; aHi += hi;
            bf2x(m7, lo, hi); aLo += lo; aHi += hi;
        }
        for (; j < cnt; ++j) {
            int s = __shfl(myIdx, j);
            unsigned m = xwp[(size_t)s * 64 + c];
            float lo, hi;
            bf2x(m, lo, hi); aLo += lo; aHi += hi;
        }
    }

    float di = dinv[n];
    float2 bv = ((const float2*)b)[c];
    h16[(size_t)n * 64 + c] = pack2(aLo * di + bv.x, aHi * di + bv.y);
}

// ---------------------------------------------------------------------------
// K6a: proj[n][0..4] = h[n] @ W_top, proj[n][5..9] = h[n] @ W_bot (fp32, MFMA)
//      proj padded to 16 cols (cols 10-15 are zero).
// ---------------------------------------------------------------------------
__global__ __launch_bounds__(256) void k_proj(const unsigned short* __restrict__ h16,
                                              const unsigned short* __restrict__ w2t,
                                              float* __restrict__ proj) {
    __shared__ char sm[16384 + 4096];
    const int tid = threadIdx.x;
    const int r0 = blockIdx.x * 64;
    {   // stage h rows 64x128 bf16 (swizzled)
        const uint4* h4 = (const uint4*)h16;
#pragma unroll
        for (int i = 0; i < 4; ++i) {
            int f = i * 256 + tid;
            int row = f >> 4;
            int kq = f & 15;
            int grow = r0 + row;
            uint4 v = make_uint4(0u, 0u, 0u, 0u);
            if (grow < N_NODES) v = h4[(size_t)grow * 16 + kq];
            *(uint4*)(sm + row * 256 + ((kq * 16) ^ ((row & 7) << 4))) = v;
        }
    }
    {   // stage w2t 16x128 bf16 (swizzled)
        const uint4* w4 = (const uint4*)w2t;
        int n = tid >> 4, kq = tid & 15;
        uint4 v = w4[tid];
        *(uint4*)(sm + 16384 + n * 256 + ((kq * 16) ^ ((n & 7) << 4))) = v;
    }
    __syncthreads();

    const int w = tid >> 6, l = tid & 63, lm = l & 15, g = l >> 4;
    f32x4 acc = (f32x4){0.f, 0.f, 0.f, 0.f};
#pragma unroll
    for (int kc = 0; kc < 4; ++kc) {
        int row = w * 16 + lm;
        int kb = kc * 64 + g * 16;
        bf16x8 a = *(const bf16x8*)(sm + row * 256 + (kb ^ ((row & 7) << 4)));
        bf16x8 b = *(const bf16x8*)(sm + 16384 + lm * 256 + (kb ^ ((lm & 7) << 4)));
        acc = __builtin_amdgcn_mfma_f32_16x16x32_bf16(a, b, acc, 0, 0, 0);
    }
#pragma unroll
    for (int r = 0; r < 4; ++r) {
        int row = r0 + w * 16 + g * 4 + r;
        if (row < N_NODES) proj[row * 16 + lm] = acc[r];
    }
}

// K6b: out[l][o] = proj[d][o] + proj[p][5+o] + b[o]
__global__ __launch_bounds__(256) void k_link2(const int* __restrict__ eli,
                                               const float* __restrict__ proj,
                                               const float* __restrict__ bl,
                                               float* __restrict__ out) {
    int t = blockIdx.x * 256 + threadIdx.x;
    int l = t >> 3, o = t & 7;
    if (l >= N_LABEL || o >= OUT) return;
    int d = eli[l];
    int p = eli[N_LABEL + l];
    out[l * OUT + o] = proj[d * 16 + o] + proj[p * 16 + OUT + o] + bl[o];
}

// ---------------------------------------------------------------------------
extern "C" void kernel_launch(void* const* d_in, const int* in_sizes, int n_in,
                              void* d_out, int out_size, void* d_ws, size_t ws_size,
                              hipStream_t stream) {
    const float* x     = (const float*)d_in[0];
    const int*   ei    = (const int*)d_in[1];
    const int*   eli   = (const int*)d_in[2];
    const float* W_gcn = (const float*)d_in[3];
    const float* b_gcn = (const float*)d_in[4];
    const float* W_lin = (const float*)d_in[5];
    const float* b_lin = (const float*)d_in[6];
    float* out = (float*)d_out;

    // workspace layout (8B-aligned segments)
    unsigned short* xwh = (unsigned short*)d_ws;               // 12.8M u16 (25.6 MB)
    unsigned short* h16 = xwh + (size_t)N_NODES * HID;         // 12.8M u16 (25.6 MB)
    int2* bedge      = (int2*)(h16 + (size_t)N_NODES * HID);   // 1.6M int2 (12.8 MB)
    int2* seg        = bedge + N_EDGES;                        // 100k int2
    float* proj      = (float*)(seg + N_NODES);                // 1.6M f32 (6.4 MB)
    int*   csr       = (int*)(proj + (size_t)N_NODES * 16);    // 1.6M int
    float* dinv      = (float*)(csr + N_EDGES);                // 100k f32
    int*   hist      = (int*)(dinv + N_NODES);                 // 391*782 int
    int*   btot      = hist + NBUCK * NBLK_E;                  // 391 int
    int*   bbase     = btot + NBUCK;                           // 392 int
    unsigned short* wt  = (unsigned short*)(bbase + NBUCK + 1 + 3); // 16384 u16
    unsigned short* w2t = wt + HID * HID;                      // 2048 u16

    // weight prep
    k_prep<<<HID, HID, 0, stream>>>(W_gcn, wt);
    k_prep2<<<16, HID, 0, stream>>>(W_lin, w2t);
    // CSR build (atomic-free)
    k_hist<<<NBLK_E, 256, 0, stream>>>(ei, hist);
    k_scanb<<<NBUCK, 256, 0, stream>>>(hist, btot);
    k_base<<<1, 512, 0, stream>>>(btot, bbase);
    k_part<<<NBLK_E, 256, 0, stream>>>(ei, hist, bbase, bedge);
    k_build<<<NBUCK, 256, 0, stream>>>(bedge, bbase, csr, seg, dinv);
    // xwh = bf16((x @ W_gcn) * dinv) via MFMA
    k_gemm<<<(N_NODES + 63) / 64, 256, 0, stream>>>(x, wt, dinv, xwh);
    // pull aggregation
    k_pull<<<(int)(((size_t)N_NODES * 64 + 255) / 256), 256, 0, stream>>>(
        (const unsigned*)xwh, seg, csr, dinv, b_gcn, (unsigned*)h16);
    // link head: per-node projection + gather-add
    k_proj<<<(N_NODES + 63) / 64, 256, 0, stream>>>(h16, w2t, proj);
    k_link2<<<(N_LABEL * 8 + 255) / 256, 256, 0, stream>>>(eli, proj, b_lin, out);
}

// Round 10
// 166.598 us; speedup vs baseline: 1.6116x; 1.0141x over previous
//
#include <hip/hip_runtime.h>

#define N_NODES 100000
#define N_EDGES 1600000
#define N_LABEL 200000
#define HID 128
#define OUT 5

#define NBUCK 391        // ceil(N_NODES/256)
#define EPB   2048       // edges per partition block
#define NBLK_E 782       // ceil(N_EDGES/EPB)

typedef __attribute__((ext_vector_type(8))) short bf16x8;
typedef __attribute__((ext_vector_type(4))) float f32x4;

// ---- bf16 helpers (manual, RNE) -------------------------------------------
__device__ inline void bf2x(unsigned u, float& lo, float& hi) {
    lo = __uint_as_float(u << 16);
    hi = __uint_as_float(u & 0xffff0000u);
}
__device__ inline unsigned pack2(float a, float b) {
    unsigned ua = __float_as_uint(a), ub = __float_as_uint(b);
    ua = (ua + 0x7fffu + ((ua >> 16) & 1u)) >> 16;
    ub = (ub + 0x7fffu + ((ub >> 16) & 1u)) & 0xffff0000u;
    return ua | ub;
}
__device__ inline unsigned short bf1(float f) {
    unsigned u = __float_as_uint(f);
    return (unsigned short)((u + 0x7fffu + ((u >> 16) & 1u)) >> 16);
}

// ---------------------------------------------------------------------------
// K0: weight prep (merged). blocks 0-127: wt[n][k]=bf16(W_gcn[k][n]);
//     blocks 128-143: w2t[j][k] = bf16 of W_lin column j (top/bot halves).
// ---------------------------------------------------------------------------
__global__ void k_prep(const float* __restrict__ Wg, const float* __restrict__ Wl,
                       unsigned short* __restrict__ wt, unsigned short* __restrict__ w2t) {
    int bid = blockIdx.x;
    int k = threadIdx.x;
    if (bid < HID) {
        wt[bid * HID + k] = bf1(Wg[k * HID + bid]);
    } else {
        int j = bid - HID;   // 0..15
        float v = 0.f;
        if (j < OUT) v = Wl[k * OUT + j];
        else if (j < 2 * OUT) v = Wl[(HID + k) * OUT + (j - OUT)];
        w2t[j * HID + k] = bf1(v);
    }
}

// ---------------------------------------------------------------------------
// CSR build, atomic-free (global). Buckets = node>>8 (391 buckets x 256 nodes).
// bedge packed: src (20 bits) | (dst&255) << 20.
// ---------------------------------------------------------------------------
__global__ __launch_bounds__(256) void k_hist(const int* __restrict__ ei,
                                              int* __restrict__ hist) {
    __shared__ int h[NBUCK];
    const int t = threadIdx.x, b = blockIdx.x;
    for (int i = t; i < NBUCK; i += 256) h[i] = 0;
    __syncthreads();
    const int e0 = b * EPB;
#pragma unroll
    for (int i = 0; i < 8; ++i) {
        int e = e0 + i * 256 + t;
        if (e < N_EDGES) atomicAdd(&h[ei[N_EDGES + e] >> 8], 1);
    }
    __syncthreads();
    for (int i = t; i < NBUCK; i += 256) hist[i * NBLK_E + b] = h[i];
}

__global__ __launch_bounds__(256) void k_scanb(int* __restrict__ hist,
                                               int* __restrict__ btot) {
    __shared__ int part[256];
    const int b = blockIdx.x, t = threadIdx.x;
    int* row = hist + b * NBLK_E;
    const int lo = t * 4, hi = min(lo + 4, NBLK_E);
    int v[4]; int s = 0;
    for (int i = lo; i < hi; ++i) { v[i - lo] = row[i]; s += v[i - lo]; }
    part[t] = s;
    __syncthreads();
#pragma unroll
    for (int off = 1; off < 256; off <<= 1) {
        int a = (t >= off) ? part[t - off] : 0;
        __syncthreads();
        part[t] += a;
        __syncthreads();
    }
    int run = part[t] - s;
    for (int i = lo; i < hi; ++i) { int x = v[i - lo]; row[i] = run; run += x; }
    if (t == 255) btot[b] = part[255];
}

__global__ __launch_bounds__(512) void k_base(const int* __restrict__ btot,
                                              int* __restrict__ bbase) {
    __shared__ int part[512];
    const int t = threadIdx.x;
    int v = (t < NBUCK) ? btot[t] : 0;
    part[t] = v;
    __syncthreads();
#pragma unroll
    for (int off = 1; off < 512; off <<= 1) {
        int a = (t >= off) ? part[t - off] : 0;
        __syncthreads();
        part[t] += a;
        __syncthreads();
    }
    if (t < NBUCK) bbase[t] = part[t] - v;
    if (t == 511) bbase[NBUCK] = part[511];
}

__global__ __launch_bounds__(256) void k_part(const int* __restrict__ ei,
                                              const int* __restrict__ hist,
                                              const int* __restrict__ bbase,
                                              unsigned* __restrict__ bedge) {
    __shared__ int cur[NBUCK];
    const int t = threadIdx.x, b = blockIdx.x;
    for (int i = t; i < NBUCK; i += 256) cur[i] = bbase[i] + hist[i * NBLK_E + b];
    __syncthreads();
    const int e0 = b * EPB;
#pragma unroll
    for (int i = 0; i < 8; ++i) {
        int e = e0 + i * 256 + t;
        if (e < N_EDGES) {
            int dst = ei[N_EDGES + e];
            unsigned src = (unsigned)ei[e];
            int pos = atomicAdd(&cur[dst >> 8], 1);
            bedge[pos] = src | ((unsigned)(dst & 255) << 20);
        }
    }
}

__global__ __launch_bounds__(256) void k_build(const unsigned* __restrict__ bedge,
                                               const int* __restrict__ bbase,
                                               int* __restrict__ csr,
                                               int2* __restrict__ seg,
                                               float* __restrict__ dinv) {
    __shared__ int cnt[256];
    __shared__ int nb[256];
    __shared__ int cursor[256];
    const int b = blockIdx.x, t = threadIdx.x;
    const int base = bbase[b];
    const int size = bbase[b + 1] - base;
    cnt[t] = 0;
    __syncthreads();
    for (int i = t; i < size; i += 256) atomicAdd(&cnt[bedge[base + i] >> 20], 1);
    __syncthreads();
    const int c = cnt[t];
    nb[t] = c;
    __syncthreads();
#pragma unroll
    for (int off = 1; off < 256; off <<= 1) {
        int a = (t >= off) ? nb[t - off] : 0;
        __syncthreads();
        nb[t] += a;
        __syncthreads();
    }
    const int myBase = nb[t] - c;
    cursor[t] = myBase;
    __syncthreads();
    for (int i = t; i < size; i += 256) {
        unsigned v = bedge[base + i];
        int pos = atomicAdd(&cursor[v >> 20], 1);
        csr[base + pos] = (int)(v & 0xFFFFFu);
    }
    const int n = b * 256 + t;
    if (n < N_NODES) {
        seg[n] = make_int2(base + myBase, c);
        dinv[n] = rsqrtf((float)(c + 1));
    }
}

// ---------------------------------------------------------------------------
// K1: xwh = bf16( (x @ W) * dinv[row] )  via MFMA 16x16x32 bf16.
// ---------------------------------------------------------------------------
__global__ __launch_bounds__(256) void k_gemm(const float* __restrict__ x,
                                              const unsigned short* __restrict__ wt,
                                              const float* __restrict__ dinv,
                                              unsigned short* __restrict__ xwh) {
    __shared__ char sm[49152];  // xs bf16[64][128] @0; Wt bf16[128][128] @16384
    const int tid = threadIdx.x;
    const int r0 = blockIdx.x * 64;

    {   // stage W^T
        const uint4* w4 = (const uint4*)wt;
#pragma unroll
        for (int i = 0; i < 8; ++i) {
            int f = i * 256 + tid;
            int n = f >> 4;
            int kq = f & 15;
            uint4 v = w4[f];
            *(uint4*)(sm + 16384 + n * 256 + ((kq * 16) ^ ((n & 7) << 4))) = v;
        }
    }
    {   // stage x tile -> bf16
        const float4* x4 = (const float4*)x;
#pragma unroll
        for (int i = 0; i < 8; ++i) {
            int f = i * 256 + tid;
            int row = f >> 5;
            int kq = f & 31;
            int grow = r0 + row;
            float4 gv;
            if (grow < N_NODES) gv = x4[(size_t)grow * 32 + kq];
            else { gv.x = 0.f; gv.y = 0.f; gv.z = 0.f; gv.w = 0.f; }
            uint2 p;
            p.x = pack2(gv.x, gv.y);
            p.y = pack2(gv.z, gv.w);
            *(uint2*)(sm + row * 256 + ((kq * 8) ^ ((row & 7) << 4))) = p;
        }
    }
    __syncthreads();

    const int w = tid >> 6;
    const int l = tid & 63;
    const int lm = l & 15;
    const int g = l >> 4;

    bf16x8 a[4];
#pragma unroll
    for (int kc = 0; kc < 4; ++kc) {
        int row = w * 16 + lm;
        int kb = kc * 64 + g * 16;
        a[kc] = *(const bf16x8*)(sm + row * 256 + (kb ^ ((row & 7) << 4)));
    }

    f32x4 accs[8];
#pragma unroll
    for (int nt = 0; nt < 8; ++nt) accs[nt] = (f32x4){0.f, 0.f, 0.f, 0.f};

#pragma unroll
    for (int nt = 0; nt < 8; ++nt) {
        int n = nt * 16 + lm;
        const char* bp = sm + 16384 + n * 256;
        int msk = (n & 7) << 4;
#pragma unroll
        for (int kc = 0; kc < 4; ++kc) {
            int kb = kc * 64 + g * 16;
            bf16x8 b = *(const bf16x8*)(bp + (kb ^ msk));
            accs[nt] = __builtin_amdgcn_mfma_f32_16x16x32_bf16(a[kc], b, accs[nt], 0, 0, 0);
        }
    }

    float dv[4];
#pragma unroll
    for (int r = 0; r < 4; ++r) {
        int row = r0 + w * 16 + g * 4 + r;
        dv[r] = (row < N_NODES) ? dinv[row] : 0.f;
    }

#pragma unroll
    for (int nt = 0; nt < 8; ++nt) {
        int col = nt * 16 + lm;
#pragma unroll
        for (int r = 0; r < 4; ++r) {
            int row = r0 + w * 16 + g * 4 + r;
            if (row < N_NODES) xwh[(size_t)row * HID + col] = bf1(accs[nt][r] * dv[r]);
        }
    }
}

// ---------------------------------------------------------------------------
// K5: FUSED pull-aggregate + projection. 1024 threads = 16 waves = 16 nodes.
//     Each wave: one node's pull (coalesced csr + shfl broadcast, 8x MLP),
//     h-row -> padded LDS [16][66] (bank-conflict-free). Then wave 0 computes
//     proj[16 nodes][16 outs] = h @ w2t^T with 4 MFMAs. h never hits global.
// ---------------------------------------------------------------------------
__global__ __launch_bounds__(1024) void k_pullproj(const unsigned* __restrict__ xwp,
                                                   const int2* __restrict__ seg,
                                                   const int* __restrict__ csr,
                                                   const float* __restrict__ dinv,
                                                   const float* __restrict__ b,
                                                   const unsigned* __restrict__ w2t,
                                                   float* __restrict__ proj) {
    __shared__ unsigned hs[16][66];   // h rows, bf16x2 per uint, +2 pad
    __shared__ unsigned ws[16][66];   // w2t rows (16 outs x 128 bf16)
    const int tid = threadIdx.x;
    const int r0 = blockIdx.x * 16;

    ws[tid >> 6][tid & 63] = w2t[tid];   // 1024 uints, one per thread

    const int wv = tid >> 6;   // wave = node within tile
    const int c = tid & 63;    // dword lane (cols 2c, 2c+1)
    const int n = r0 + wv;     // N_NODES % 16 == 0, always valid

    float aLo, aHi;
    bf2x(xwp[(size_t)n * 64 + c], aLo, aHi);   // self term (carries dinv[n])

    const int2 sg = seg[n];
    const int beg = sg.x;
    const int deg = sg.y;

    for (int base = 0; base < deg; base += 64) {
        const int cnt = min(64, deg - base);
        int myIdx = (c < cnt) ? csr[beg + base + c] : 0;
        int j = 0;
        for (; j + 8 <= cnt; j += 8) {
            int s0 = __shfl(myIdx, j);
            int s1 = __shfl(myIdx, j + 1);
            int s2 = __shfl(myIdx, j + 2);
            int s3 = __shfl(myIdx, j + 3);
            int s4 = __shfl(myIdx, j + 4);
            int s5 = __shfl(myIdx, j + 5);
            int s6 = __shfl(myIdx, j + 6);
            int s7 = __shfl(myIdx, j + 7);
            unsigned m0 = xwp[(size_t)s0 * 64 + c];
            unsigned m1 = xwp[(size_t)s1 * 64 + c];
            unsigned m2 = xwp[(size_t)s2 * 64 + c];
            unsigned m3 = xwp[(size_t)s3 * 64 + c];
            unsigned m4 = xwp[(size_t)s4 * 64 + c];
            unsigned m5 = xwp[(size_t)s5 * 64 + c];
            unsigned m6 = xwp[(size_t)s6 * 64 + c];
            unsigned m7 = xwp[(size_t)s7 * 64 + c];
            float lo, hi;
            bf2x(m0, lo, hi); aLo += lo; aHi += hi;
            bf2x(m1, lo, hi); aLo += lo; aHi += hi;
            bf2x(m2, lo, hi); aLo += lo; aHi += hi;
            bf2x(m3, lo, hi); aLo += lo; aHi += hi;
            bf2x(m4, lo, hi); aLo += lo; aHi += hi;
            bf2x(m5, lo, hi); aLo += lo; aHi += hi;
            bf2x(m6, lo, hi); aLo += lo; aHi += hi;
            bf2x(m7, lo, hi); aLo += lo; aHi += hi;
        }
        for (; j < cnt; ++j) {
            int s = __shfl(myIdx, j);
            unsigned m = xwp[(size_t)s * 64 + c];
            float lo, hi;
            bf2x(m, lo, hi); aLo += lo; aHi += hi;
        }
    }

    float di = dinv[n];
    float2 bv = ((const float2*)b)[c];
    hs[wv][c] = pack2(aLo * di + bv.x, aHi * di + bv.y);
    __syncthreads();

    if (tid < 64) {   // wave 0: proj = h @ w2t^T via 4 MFMAs
        const int lm = tid & 15, g = tid >> 4;
        f32x4 acc = (f32x4){0.f, 0.f, 0.f, 0.f};
#pragma unroll
        for (int kc = 0; kc < 4; ++kc) {
            bf16x8 a = *(const bf16x8*)&hs[lm][kc * 16 + g * 4];   // A: row=node lm
            bf16x8 w = *(const bf16x8*)&ws[lm][kc * 16 + g * 4];   // B: col=out lm
            acc = __builtin_amdgcn_mfma_f32_16x16x32_bf16(a, w, acc, 0, 0, 0);
        }
#pragma unroll
        for (int r = 0; r < 4; ++r)
            proj[(size_t)(r0 + g * 4 + r) * 16 + lm] = acc[r];
    }
}

// ---------------------------------------------------------------------------
// K6: out[l][o] = proj[d][o] + proj[p][5+o] + b[o]
// ---------------------------------------------------------------------------
__global__ __launch_bounds__(256) void k_link2(const int* __restrict__ eli,
                                               const float* __restrict__ proj,
                                               const float* __restrict__ bl,
                                               float* __restrict__ out) {
    int t = blockIdx.x * 256 + threadIdx.x;
    int l = t >> 3, o = t & 7;
    if (l >= N_LABEL || o >= OUT) return;
    int d = eli[l];
    int p = eli[N_LABEL + l];
    out[l * OUT + o] = proj[d * 16 + o] + proj[p * 16 + OUT + o] + bl[o];
}

// ---------------------------------------------------------------------------
extern "C" void kernel_launch(void* const* d_in, const int* in_sizes, int n_in,
                              void* d_out, int out_size, void* d_ws, size_t ws_size,
                              hipStream_t stream) {
    const float* x     = (const float*)d_in[0];
    const int*   ei    = (const int*)d_in[1];
    const int*   eli   = (const int*)d_in[2];
    const float* W_gcn = (const float*)d_in[3];
    const float* b_gcn = (const float*)d_in[4];
    const float* W_lin = (const float*)d_in[5];
    const float* b_lin = (const float*)d_in[6];
    float* out = (float*)d_out;

    // workspace layout
    unsigned short* xwh = (unsigned short*)d_ws;               // 12.8M u16 (25.6 MB)
    unsigned* bedge  = (unsigned*)(xwh + (size_t)N_NODES * HID); // 1.6M u32 (6.4 MB)
    int2* seg        = (int2*)(bedge + N_EDGES);               // 100k int2
    float* proj      = (float*)(seg + N_NODES);                // 1.6M f32 (6.4 MB)
    int*   csr       = (int*)(proj + (size_t)N_NODES * 16);    // 1.6M int
    float* dinv      = (float*)(csr + N_EDGES);                // 100k f32
    int*   hist      = (int*)(dinv + N_NODES);                 // 391*782 int
    int*   btot      = hist + NBUCK * NBLK_E;                  // 391 int
    int*   bbase     = btot + NBUCK;                           // 392 int
    unsigned short* wt  = (unsigned short*)(bbase + NBUCK + 1 + 3); // 16384 u16
    unsigned short* w2t = wt + HID * HID;                      // 2048 u16

    // weight prep (merged)
    k_prep<<<HID + 16, HID, 0, stream>>>(W_gcn, W_lin, wt, w2t);
    // CSR build (atomic-free, packed bedge)
    k_hist<<<NBLK_E, 256, 0, stream>>>(ei, hist);
    k_scanb<<<NBUCK, 256, 0, stream>>>(hist, btot);
    k_base<<<1, 512, 0, stream>>>(btot, bbase);
    k_part<<<NBLK_E, 256, 0, stream>>>(ei, hist, bbase, bedge);
    k_build<<<NBUCK, 256, 0, stream>>>(bedge, bbase, csr, seg, dinv);
    // xwh = bf16((x @ W_gcn) * dinv) via MFMA
    k_gemm<<<(N_NODES + 63) / 64, 256, 0, stream>>>(x, wt, dinv, xwh);
    // fused pull + projection (h never touches global memory)
    k_pullproj<<<N_NODES / 16, 1024, 0, stream>>>(
        (const unsigned*)xwh, seg, csr, dinv, b_gcn, (const unsigned*)w2t, proj);
    // link head: gather-add of projected rows
    k_link2<<<(N_LABEL * 8 + 255) / 256, 256, 0, stream>>>(eli, proj, b_lin, out);
}

// Round 11
// 115.569 us; speedup vs baseline: 2.3232x; 1.4415x over previous
//
#include <hip/hip_runtime.h>

#define N_NODES 100000
#define N_EDGES 1600000
#define N_LABEL 200000
#define HID 128
#define OUT 5

#define NBUCK 391        // ceil(N_NODES/256)
#define EPB   2048       // edges per partition block
#define NBLK_E 782       // ceil(N_EDGES/EPB)

// ---------------------------------------------------------------------------
// The whole net is LINEAR: out = [h_d | h_p] @ W_lin + b_lin,
//   h = dinv_n * (sum_src xw_src*dinv_src + xw_n*dinv_n) + b_gcn.
// Define W2[c][j] (128x10) = [W_lin top | W_lin bottom] columns,
//   G = W_gcn @ W2  (128x10),  c0[j] = b_gcn @ W2.
// Then t[n] = dinv_n * (x[n] @ G)      (10 floats per node, padded to 16)
//      proj[n] = dinv_n * (sum_{src in N(n)} t[src] + t[n]) + c0
//      out[l][o] = proj[d][o] + proj[p][5+o] + b_lin[o].
// Per-edge gather: 40B (one cache line) from a 6.4MB L2-resident table.
// ---------------------------------------------------------------------------

// K0: G[r*16+j] = sum_c W_gcn[r][c]*W2[c][j];  row 128 holds c0 (b_gcn @ W2).
__global__ __launch_bounds__(256) void k_precomp(const float* __restrict__ Wg,
                                                 const float* __restrict__ bg,
                                                 const float* __restrict__ Wl,
                                                 float* __restrict__ G) {
    int o = blockIdx.x * 256 + threadIdx.x;
    if (o >= 129 * 16) return;
    int r = o >> 4, jj = o & 15;
    float acc = 0.f;
    if (jj < 2 * OUT) {
        const int half = (jj >= OUT);
        const int j = half ? jj - OUT : jj;
        for (int c = 0; c < HID; ++c) {
            float w2 = Wl[(half * HID + c) * OUT + j];
            float a = (r < HID) ? Wg[r * HID + c] : bg[c];
            acc += a * w2;
        }
    }
    G[o] = acc;
}

// ---------------------------------------------------------------------------
// CSR build, atomic-free (global). Buckets = node>>8 (391 buckets x 256 nodes).
// bedge packed: src (20 bits) | (dst&255) << 20.
// ---------------------------------------------------------------------------
__global__ __launch_bounds__(256) void k_hist(const int* __restrict__ ei,
                                              int* __restrict__ hist) {
    __shared__ int h[NBUCK];
    const int t = threadIdx.x, b = blockIdx.x;
    for (int i = t; i < NBUCK; i += 256) h[i] = 0;
    __syncthreads();
    const int e0 = b * EPB;
#pragma unroll
    for (int i = 0; i < 8; ++i) {
        int e = e0 + i * 256 + t;
        if (e < N_EDGES) atomicAdd(&h[ei[N_EDGES + e] >> 8], 1);
    }
    __syncthreads();
    for (int i = t; i < NBUCK; i += 256) hist[i * NBLK_E + b] = h[i];
}

__global__ __launch_bounds__(256) void k_scanb(int* __restrict__ hist,
                                               int* __restrict__ btot) {
    __shared__ int part[256];
    const int b = blockIdx.x, t = threadIdx.x;
    int* row = hist + b * NBLK_E;
    const int lo = t * 4, hi = min(lo + 4, NBLK_E);
    int v[4]; int s = 0;
    for (int i = lo; i < hi; ++i) { v[i - lo] = row[i]; s += v[i - lo]; }
    part[t] = s;
    __syncthreads();
#pragma unroll
    for (int off = 1; off < 256; off <<= 1) {
        int a = (t >= off) ? part[t - off] : 0;
        __syncthreads();
        part[t] += a;
        __syncthreads();
    }
    int run = part[t] - s;
    for (int i = lo; i < hi; ++i) { int x = v[i - lo]; row[i] = run; run += x; }
    if (t == 255) btot[b] = part[255];
}

__global__ __launch_bounds__(512) void k_base(const int* __restrict__ btot,
                                              int* __restrict__ bbase) {
    __shared__ int part[512];
    const int t = threadIdx.x;
    int v = (t < NBUCK) ? btot[t] : 0;
    part[t] = v;
    __syncthreads();
#pragma unroll
    for (int off = 1; off < 512; off <<= 1) {
        int a = (t >= off) ? part[t - off] : 0;
        __syncthreads();
        part[t] += a;
        __syncthreads();
    }
    if (t < NBUCK) bbase[t] = part[t] - v;
    if (t == 511) bbase[NBUCK] = part[511];
}

__global__ __launch_bounds__(256) void k_part(const int* __restrict__ ei,
                                              const int* __restrict__ hist,
                                              const int* __restrict__ bbase,
                                              unsigned* __restrict__ bedge) {
    __shared__ int cur[NBUCK];
    const int t = threadIdx.x, b = blockIdx.x;
    for (int i = t; i < NBUCK; i += 256) cur[i] = bbase[i] + hist[i * NBLK_E + b];
    __syncthreads();
    const int e0 = b * EPB;
#pragma unroll
    for (int i = 0; i < 8; ++i) {
        int e = e0 + i * 256 + t;
        if (e < N_EDGES) {
            int dst = ei[N_EDGES + e];
            unsigned src = (unsigned)ei[e];
            int pos = atomicAdd(&cur[dst >> 8], 1);
            bedge[pos] = src | ((unsigned)(dst & 255) << 20);
        }
    }
}

__global__ __launch_bounds__(256) void k_build(const unsigned* __restrict__ bedge,
                                               const int* __restrict__ bbase,
                                               int* __restrict__ csr,
                                               int2* __restrict__ seg,
                                               float* __restrict__ dinv) {
    __shared__ int cnt[256];
    __shared__ int nb[256];
    __shared__ int cursor[256];
    const int b = blockIdx.x, t = threadIdx.x;
    const int base = bbase[b];
    const int size = bbase[b + 1] - base;
    cnt[t] = 0;
    __syncthreads();
    for (int i = t; i < size; i += 256) atomicAdd(&cnt[bedge[base + i] >> 20], 1);
    __syncthreads();
    const int c = cnt[t];
    nb[t] = c;
    __syncthreads();
#pragma unroll
    for (int off = 1; off < 256; off <<= 1) {
        int a = (t >= off) ? nb[t - off] : 0;
        __syncthreads();
        nb[t] += a;
        __syncthreads();
    }
    const int myBase = nb[t] - c;
    cursor[t] = myBase;
    __syncthreads();
    for (int i = t; i < size; i += 256) {
        unsigned v = bedge[base + i];
        int pos = atomicAdd(&cursor[v >> 20], 1);
        csr[base + pos] = (int)(v & 0xFFFFFu);
    }
    const int n = b * 256 + t;
    if (n < N_NODES) {
        seg[n] = make_int2(base + myBase, c);
        dinv[n] = rsqrtf((float)(c + 1));
    }
}

// ---------------------------------------------------------------------------
// K_t: t[n][0..9] = dinv[n] * (x[n] @ G), rows padded to 16 (cols 10-15 = 0).
//      16 lanes per node: lane i owns k = i+16m (m=0..7); coalesced x loads;
//      G staged in LDS stride 11 (conflict-free: 11i mod 32 distinct for i<16).
// ---------------------------------------------------------------------------
__global__ __launch_bounds__(256) void k_t(const float* __restrict__ x,
                                           const float* __restrict__ G,
                                           const float* __restrict__ dinv,
                                           float* __restrict__ t) {
    __shared__ float Gs[HID * 11];
    const int tid = threadIdx.x;
    for (int o = tid; o < HID * 10; o += 256) {
        int k = o / 10, j = o - k * 10;
        Gs[k * 11 + j] = G[k * 16 + j];
    }
    __syncthreads();

    int gid = blockIdx.x * 256 + tid;
    int n = gid >> 4;          // 16 nodes per block
    int i = gid & 15;

    float xv[8];
#pragma unroll
    for (int m = 0; m < 8; ++m) xv[m] = x[(size_t)n * HID + i + 16 * m];

    float p[10];
#pragma unroll
    for (int j = 0; j < 10; ++j) p[j] = 0.f;
#pragma unroll
    for (int m = 0; m < 8; ++m) {
        const float* g = &Gs[(i + 16 * m) * 11];
#pragma unroll
        for (int j = 0; j < 10; ++j) p[j] += xv[m] * g[j];
    }
    // reduce across the 16-lane group (xor offsets stay in-group)
#pragma unroll
    for (int off = 1; off < 16; off <<= 1) {
#pragma unroll
        for (int j = 0; j < 10; ++j) p[j] += __shfl_xor(p[j], off);
    }
    float val = (i == 0) ? p[0] : (i == 1) ? p[1] : (i == 2) ? p[2] : (i == 3) ? p[3] :
                (i == 4) ? p[4] : (i == 5) ? p[5] : (i == 6) ? p[6] : (i == 7) ? p[7] :
                (i == 8) ? p[8] : (i == 9) ? p[9] : 0.f;
    t[(size_t)n * 16 + i] = dinv[n] * val;   // pads (i>=10) write 0
}

// ---------------------------------------------------------------------------
// K_pullt: proj[n] = dinv[n] * (sum_src t[src] + t[n]) + c0.
//     16 lanes per node; per edge: one 64B line gather (16 lanes x 4B);
//     csr block-loaded 16-at-a-time and shfl-broadcast; 4x unrolled MLP.
// ---------------------------------------------------------------------------
__global__ __launch_bounds__(256) void k_pullt(const float* __restrict__ t,
                                               const int2* __restrict__ seg,
                                               const int* __restrict__ csr,
                                               const float* __restrict__ dinv,
                                               const float* __restrict__ G,
                                               float* __restrict__ proj) {
    int gid = blockIdx.x * 256 + threadIdx.x;
    int n = gid >> 4;
    int i = gid & 15;
    const int gbase = threadIdx.x & 48;   // 16-lane group base within wave

    float acc = t[(size_t)n * 16 + i];    // self term
    const int2 sg = seg[n];
    const int beg = sg.x, deg = sg.y;

    for (int base = 0; base < deg; base += 16) {
        const int cnt = min(16, deg - base);
        int idx = (i < cnt) ? csr[beg + base + i] : 0;
        int j = 0;
        for (; j + 4 <= cnt; j += 4) {
            int s0 = __shfl(idx, gbase + j);
            int s1 = __shfl(idx, gbase + j + 1);
            int s2 = __shfl(idx, gbase + j + 2);
            int s3 = __shfl(idx, gbase + j + 3);
            float v0 = t[(size_t)s0 * 16 + i];
            float v1 = t[(size_t)s1 * 16 + i];
            float v2 = t[(size_t)s2 * 16 + i];
            float v3 = t[(size_t)s3 * 16 + i];
            acc += v0; acc += v1; acc += v2; acc += v3;
        }
        for (; j < cnt; ++j) {
            int s = __shfl(idx, gbase + j);
            acc += t[(size_t)s * 16 + i];
        }
    }
    proj[(size_t)n * 16 + i] = dinv[n] * acc + G[HID * 16 + i];   // + c0 (0-padded)
}

// ---------------------------------------------------------------------------
// K_link: out[l][o] = proj[d][o] + proj[p][5+o] + b_lin[o]
// ---------------------------------------------------------------------------
__global__ __launch_bounds__(256) void k_link2(const int* __restrict__ eli,
                                               const float* __restrict__ proj,
                                               const float* __restrict__ bl,
                                               float* __restrict__ out) {
    int t = blockIdx.x * 256 + threadIdx.x;
    int l = t >> 3, o = t & 7;
    if (l >= N_LABEL || o >= OUT) return;
    int d = eli[l];
    int p = eli[N_LABEL + l];
    out[l * OUT + o] = proj[d * 16 + o] + proj[p * 16 + OUT + o] + bl[o];
}

// ---------------------------------------------------------------------------
extern "C" void kernel_launch(void* const* d_in, const int* in_sizes, int n_in,
                              void* d_out, int out_size, void* d_ws, size_t ws_size,
                              hipStream_t stream) {
    const float* x     = (const float*)d_in[0];
    const int*   ei    = (const int*)d_in[1];
    const int*   eli   = (const int*)d_in[2];
    const float* W_gcn = (const float*)d_in[3];
    const float* b_gcn = (const float*)d_in[4];
    const float* W_lin = (const float*)d_in[5];
    const float* b_lin = (const float*)d_in[6];
    float* out = (float*)d_out;

    // workspace layout (all fp32 / int)
    float* t         = (float*)d_ws;                           // 100k x 16 f32 (6.4 MB)
    float* proj      = t + (size_t)N_NODES * 16;               // 100k x 16 f32 (6.4 MB)
    float* G         = proj + (size_t)N_NODES * 16;            // 129*16 f32
    float* dinv      = G + 129 * 16;                           // 100k f32
    unsigned* bedge  = (unsigned*)(dinv + N_NODES);            // 1.6M u32 (6.4 MB)
    int*   csr       = (int*)(bedge + N_EDGES);                // 1.6M int (6.4 MB)
    int2*  seg       = (int2*)(csr + N_EDGES);                 // 100k int2
    int*   hist      = (int*)(seg + N_NODES);                  // 391*782 int
    int*   btot      = hist + NBUCK * NBLK_E;                  // 391 int
    int*   bbase     = btot + NBUCK;                           // 392 int

    // G = W_gcn @ W2 (+ c0 row); independent of graph
    k_precomp<<<(129 * 16 + 255) / 256, 256, 0, stream>>>(W_gcn, b_gcn, W_lin, G);
    // CSR build (atomic-free)
    k_hist<<<NBLK_E, 256, 0, stream>>>(ei, hist);
    k_scanb<<<NBUCK, 256, 0, stream>>>(hist, btot);
    k_base<<<1, 512, 0, stream>>>(btot, bbase);
    k_part<<<NBLK_E, 256, 0, stream>>>(ei, hist, bbase, bedge);
    k_build<<<NBUCK, 256, 0, stream>>>(bedge, bbase, csr, seg, dinv);
    // t[n] = dinv_n * (x[n] @ G)   (reads x once, 51.2 MB)
    k_t<<<N_NODES * 16 / 256, 256, 0, stream>>>(x, G, dinv, t);
    // proj[n] = dinv_n * (sum t[src] + t[n]) + c0   (40B/edge, L2-resident)
    k_pullt<<<N_NODES * 16 / 256, 256, 0, stream>>>(t, seg, csr, dinv, G, proj);
    // out = gather-add
    k_link2<<<(N_LABEL * 8 + 255) / 256, 256, 0, stream>>>(eli, proj, b_lin, out);
}